// Round 10
// baseline (116.749 us; speedup 1.0000x reference)
//
#include <hip/hip_runtime.h>
#include <math.h>

#define HH 256
#define WW 256
#define HWSZ (HH * WW)
#define KE 4096
#define NSLICE 16
#define GSENT 1024             // empty-column sentinel: 1024^2 > max real d2 (130050)
#define NB 256                 // persistent grid: 256 blocks (<= #CUs, co-resident)
#define NT 512                 // threads per block (8 waves)

typedef unsigned long long u64;
typedef unsigned short u16;

// ---------------------------------------------------------------------------
// word_dist: distance from position p (may be <0 or >63) to the nearest set
// bit of w; GSENT if w empty. (r6-proven)
// ---------------------------------------------------------------------------
__device__ __forceinline__ int word_dist(u64 w, int p) {
    if (w == 0) return GSENT;
    int lo = __ffsll((long long)w) - 1;    // lowest set bit
    int hi = 63 - __clzll((long long)w);   // highest set bit
    if (p <= lo) return lo - p;
    if (p >= hi) return p - hi;
    u64 up = w >> p;                        // bits >= p (nonzero: hi > p)
    int du = __ffsll((long long)up) - 1;
    u64 dn = w << (63 - p);                 // bits <= p (nonzero: lo < p)
    int dd = __clzll((long long)dn);
    return min(du, dd);
}

// ---------------------------------------------------------------------------
// Hierarchical grid barrier. 8 sub-counters x 32 blocks -> 1 root per slot.
// Epoch-based (monotonic): tolerates re-execution without counter reset as
// long as counters start at a completed-state multiple (the memset node
// guarantees zeros each launch; monotonic logic additionally survives
// profiler kernel-only replays). Release/acquire chain: writer blocks
// release into arrive[sub]; sub-leader ACQ_RELs root; spinners acquire root
// -> transitive happens-before for all prior global stores (device scope,
// valid across XCDs).
// ---------------------------------------------------------------------------
__device__ __forceinline__ void grid_barrier(int* __restrict__ arrive,
                                             int* __restrict__ root,
                                             int idx, int bid) {
    __syncthreads();
    if (threadIdx.x == 0) {
        int sub = bid & 7;
        int prev = __hip_atomic_fetch_add(&arrive[idx * 8 + sub], 1,
                                          __ATOMIC_ACQ_REL,
                                          __HIP_MEMORY_SCOPE_AGENT);
        int epoch = prev >> 5;              // prev / 32
        if ((prev & 31) == 31)
            __hip_atomic_fetch_add(&root[idx], 1, __ATOMIC_ACQ_REL,
                                   __HIP_MEMORY_SCOPE_AGENT);
        while (__hip_atomic_load(&root[idx], __ATOMIC_ACQUIRE,
                                 __HIP_MEMORY_SCOPE_AGENT) < (epoch + 1) * 8)
            __builtin_amdgcn_s_sleep(1);
    }
    __syncthreads();
}

// ---------------------------------------------------------------------------
// Single persistent kernel: 5 phases (binarize/pack, edge+compact, vertical
// EDT, NN gather, finalize) separated by grid barriers. All phase bodies are
// the r6-proven implementations; only the work->block mapping changed to fit
// the 256x512 persistent grid.
// ---------------------------------------------------------------------------
__global__ void __launch_bounds__(NT) ahd_fused(
        const float* __restrict__ gth, const float* __restrict__ pred,
        u64* __restrict__ bm, u64* __restrict__ ebm,
        float2* __restrict__ gpts, float2* __restrict__ ppts,
        int* __restrict__ gcnt, int* __restrict__ pcnt,
        u16* __restrict__ G16, float* __restrict__ partial,
        int* __restrict__ arrive, int* __restrict__ root,
        float* __restrict__ out) {
    int bid = blockIdx.x;
    int tid = threadIdx.x;

    __shared__ u64 ebl[1024];               // 8 KB: phase-2 bitmap stage
    __shared__ int wsum[4];
    __shared__ float red[8];
    __shared__ float sdsum[32];

    // ======== Phase 0: binarize + bit-pack (all 256 blocks) ========
    // block = (map m, rowgroup rg): m = bid>>3 in [0,32), rg = bid&7.
    // 512 threads process 2 rows/iter (waves 0-3 row A, waves 4-7 row B).
    {
        int m = bid >> 3, rg = bid & 7;
        int tensor = m >> 4, slice = m & 15;
        const float* img = (tensor ? pred : gth) + slice * HWSZ;
        int half = tid >> 8;                // 0/1
        int col = tid & 255;
        int word = (tid >> 6) & 3;
        int lane = tid & 63;
#pragma unroll 4
        for (int i = 0; i < 16; ++i) {
            int row = rg * 32 + i * 2 + half;
            float v = img[row * WW + col];
            u64 bal = __ballot(v > 0.5f);
            if (lane == 0) bm[((size_t)m * 256 + row) * 4 + word] = bal;
        }
    }
    grid_barrier(arrive, root, 0, bid);

    // ======== Phase 1: edge detect + ordered compaction (blocks 0..31) ====
    {
        bool act = (bid < 32) && (tid < 256);
        u64 e[4];
        int mycnt = 0, incl = 0;
        int row = tid, lane = tid & 63, wv = tid >> 6;
        if (act) {
            const u64* rm = bm + (size_t)bid * 1024;
            u64 vc[4], va[4], vb[4];
#pragma unroll
            for (int w = 0; w < 4; ++w) {
                vc[w] = rm[row * 4 + w];
                va[w] = (row > 0) ? rm[(row - 1) * 4 + w] : ~0ull;
                vb[w] = (row < HH - 1) ? rm[(row + 1) * 4 + w] : ~0ull;
            }
            u64 vert[4];
#pragma unroll
            for (int w = 0; w < 4; ++w) vert[w] = va[w] & vc[w] & vb[w];
#pragma unroll
            for (int w = 0; w < 4; ++w) {
                u64 left  = (vert[w] << 1) | ((w > 0) ? (vert[w - 1] >> 63) : 1ull);
                u64 right = (vert[w] >> 1) | (((w < 3) ? (vert[w + 1] & 1ull) : 1ull) << 63);
                e[w] = vc[w] & ~(vert[w] & left & right);
            }
            mycnt = __popcll(e[0]) + __popcll(e[1]) + __popcll(e[2]) + __popcll(e[3]);

            incl = mycnt;                   // wave-level inclusive scan
            for (int d = 1; d < 64; d <<= 1) {
                int n = __shfl_up(incl, d, 64);
                if (lane >= d) incl += n;
            }
            if (lane == 63) wsum[wv] = incl;
        }
        __syncthreads();
        if (act) {
            int tensor = bid >> 4, slice = bid & 15;
            float2* pts = (tensor ? ppts : gpts) + slice * KE;
            int* cnt = (tensor ? pcnt : gcnt) + slice;
            u64* eb = ebm + (size_t)bid * 1024;

            int wpre = 0;
            for (int k = 0; k < 4; ++k) wpre += (k < wv) ? wsum[k] : 0;
            int off = wpre + incl - mycnt;  // exclusive prefix (row-major rank)

            // Truncated edge bitmap: keep only bits with rank < KE.
            int rem = KE - off;
            u64 t[4];
            if (rem >= mycnt) {
#pragma unroll
                for (int w = 0; w < 4; ++w) t[w] = e[w];
            } else if (rem <= 0) {
#pragma unroll
                for (int w = 0; w < 4; ++w) t[w] = 0ull;
            } else {
                int k = rem;
#pragma unroll
                for (int w = 0; w < 4; ++w) {
                    int pc = __popcll(e[w]);
                    if (k >= pc) { t[w] = e[w]; k -= pc; }
                    else {
                        u64 bits = e[w], keep = 0ull;
                        for (int i = 0; i < k; ++i) {
                            u64 low = bits & (~bits + 1ull);
                            keep |= low;
                            bits ^= low;
                        }
                        t[w] = keep;
                        k = 0;
                    }
                }
            }
#pragma unroll
            for (int w = 0; w < 4; ++w) eb[row * 4 + w] = t[w];

            // Ordered point-list writes (first KE in row-major order).
            int o = off;
#pragma unroll
            for (int w = 0; w < 4; ++w) {
                u64 bits = e[w];
                while (bits) {
                    int l = __ffsll((long long)bits) - 1;
                    bits &= bits - 1;
                    if (o < KE) pts[o] = make_float2((float)row, (float)(w * 64 + l));
                    ++o;
                }
            }
            if (row == HH - 1) *cnt = wpre + incl;
        }
    }
    grid_barrier(arrive, root, 1, bid);

    // ======== Phase 2: vertical EDT (all 256 blocks; r6 edt_vert) ========
    {
        int map = bid >> 3, rblk = bid & 7;
        const u64* eb = ebm + (size_t)map * 1024;
        u16* G = G16 + (size_t)map * HWSZ;
        for (int i = tid; i < 1024; i += NT) ebl[i] = eb[i];
        __syncthreads();
        if (tid < 256) {
            int c = tid, cw = c >> 6, cb = c & 63;
            u64 w0 = 0, w1 = 0, w2 = 0, w3 = 0;
#pragma unroll 4
            for (int r = 0; r < 64; ++r) {
                w0 |= ((ebl[(r      ) * 4 + cw] >> cb) & 1ull) << r;
                w1 |= ((ebl[(r +  64) * 4 + cw] >> cb) & 1ull) << r;
                w2 |= ((ebl[(r + 128) * 4 + cw] >> cb) & 1ull) << r;
                w3 |= ((ebl[(r + 192) * 4 + cw] >> cb) & 1ull) << r;
            }
            int r0 = rblk * 32;
#pragma unroll 4
            for (int i = 0; i < 32; ++i) {
                int r = r0 + i;
                int d = word_dist(w0, r);
                d = min(d, word_dist(w1, r - 64));
                d = min(d, word_dist(w2, r - 128));
                d = min(d, word_dist(w3, r - 192));
                G[r * WW + c] = (u16)min(d, GSENT);
            }
        }
    }
    grid_barrier(arrive, root, 2, bid);

    // ======== Phase 3: NN gather (all 256 blocks = 32 sd x 8 chunks) =====
    {
        int sd = bid >> 3, chunk = bid & 7;
        int dir = sd & 1, slice = sd >> 1;
        int qfull = dir ? pcnt[slice] : gcnt[slice];
        int qc = min(qfull, KE);
        int qi = chunk * NT + tid;

        float val = 0.0f;
        if (qi < qc) {
            const float2* q = (dir ? ppts : gpts) + slice * KE;
            int tt = dir ? 0 : 1;           // target map tensor
            const u16* G = G16 + (size_t)(tt * 16 + slice) * HWSZ;
            float2 qp = q[qi];
            int r = (int)qp.x, c = (int)qp.y;
            const int4* grow = (const int4*)(G + r * WW);  // 256 u16 = 32 int4
            int m = 0x7fffffff;
#pragma unroll
            for (int j = 0; j < 32; ++j) {
                int4 v = grow[j];
                int base = j * 8;
#define STEP(word, k0)                                                      \
                {                                                           \
                    int g0 = (word) & 0xffff;                               \
                    int g1 = (int)(((unsigned)(word)) >> 16);               \
                    int dc0 = c - (base + k0);                              \
                    int dc1 = c - (base + k0 + 1);                          \
                    m = min(m, dc0 * dc0 + g0 * g0);                        \
                    m = min(m, dc1 * dc1 + g1 * g1);                        \
                }
                STEP(v.x, 0) STEP(v.y, 2) STEP(v.z, 4) STEP(v.w, 6)
#undef STEP
            }
            val = sqrtf((float)m);
        }
        for (int s = 32; s > 0; s >>= 1) val += __shfl_xor(val, s, 64);
        if ((tid & 63) == 0) red[tid >> 6] = val;
        __syncthreads();
        if (tid == 0) {
            float s = 0.0f;
            for (int k = 0; k < 8; ++k) s += red[k];
            partial[bid] = s;               // plain store; barrier publishes
        }
    }
    grid_barrier(arrive, root, 3, bid);

    // ======== Phase 4: finalize (block 0) ========
    if (bid == 0) {
        if (tid < 32) {
            float s = 0.0f;
            for (int k = 0; k < 8; ++k) s += partial[tid * 8 + k];
            sdsum[tid] = s;
        }
        __syncthreads();
        if (tid == 0) {
            float sum = 0.0f;
            int nvalid = 0;
            for (int s2 = 0; s2 < NSLICE; ++s2) {
                int ng = gcnt[s2];
                int np_ = pcnt[s2];
                if (ng > 0 && np_ > 0) {
                    float ahd = 0.5f * (sdsum[s2 * 2 + 0] / (float)ng +
                                        sdsum[s2 * 2 + 1] / (float)np_);
                    sum += 1.0f - 1.0f / (1.0f + ahd);
                    nvalid++;
                }
            }
            out[0] = nvalid ? (sum / (float)nvalid) : NAN;
        }
    }
}

// ---------------------------------------------------------------------------
// Workspace layout (bytes):
//   [0,       256K)    bm      : 32 maps x 256 x 4 u64  (mask bitmaps)
//   [262144,  512K)    ebm     : 32 maps x 256 x 4 u64  (truncated edge bitmaps)
//   [524288,  1M)      gpts    : 16 x 4096 float2
//   [1048576, 1.5M)    ppts    : 16 x 4096 float2
//   [1572864, 5767168) G16     : 32 maps x 256 x 256 u16 (vertical EDT)
//   [5767168, +64)     gcnt    : 16 int
//   [5767232, +64)     pcnt    : 16 int
//   [5767296, +1K)     partial : 256 float
//   [5768320, +144)    barrier : arrive[4][8] + root[4]  (memset each launch)
// ---------------------------------------------------------------------------
extern "C" void kernel_launch(void* const* d_in, const int* in_sizes, int n_in,
                              void* d_out, int out_size, void* d_ws, size_t ws_size,
                              hipStream_t stream) {
    const float* gth = (const float*)d_in[0];
    const float* pred = (const float*)d_in[1];
    float* out = (float*)d_out;
    char* ws = (char*)d_ws;

    u64* bm = (u64*)(ws);
    u64* ebm = (u64*)(ws + 262144);
    float2* gpts = (float2*)(ws + 524288);
    float2* ppts = (float2*)(ws + 1048576);
    u16* G16 = (u16*)(ws + 1572864);
    int* gcnt = (int*)(ws + 5767168);
    int* pcnt = (int*)(ws + 5767232);
    float* partial = (float*)(ws + 5767296);
    int* arrive = (int*)(ws + 5768320);         // 32 ints
    int* root = (int*)(ws + 5768320 + 128);     // 4 ints

    hipMemsetAsync(ws + 5768320, 0, 144, stream);
    ahd_fused<<<NB, NT, 0, stream>>>(gth, pred, bm, ebm, gpts, ppts,
                                     gcnt, pcnt, G16, partial,
                                     arrive, root, out);
}

// Round 11
// 48.598 us; speedup vs baseline: 2.4023x; 2.4023x over previous
//
#include <hip/hip_runtime.h>
#include <math.h>

#define HH 256
#define WW 256
#define HWSZ (HH * WW)
#define KE 4096
#define NSLICE 16
#define NCH 64                 // query chunks of 64 per (slice,dir)
#define GSENT 1024             // empty-column sentinel: 1024^2 > max real d2 (130050)
#define RPB 32                 // rows per edt_vert block

typedef unsigned long long u64;
typedef unsigned short u16;

// ---------------------------------------------------------------------------
// K1: fused binarize + edge detect + ordered compaction (r8-proven shape,
// which r8's counters showed was NOT the regression). 32 blocks
// (tensor,slice) x 1024 threads.
// Phase 1 (all 1024 thr): coalesced read of the 256x256 slice, 4 rows per
//   iteration; per-wave ballot packs 64 cols -> u64 into LDS bitmap.
// Phase 2 (tid<256, thread=row): bitwise erosion (+inf padding semantics):
//   vert  = rowAbove & row & rowBelow      (OOB row = all-ones)
//   erode = vert & shl1 & shr1             (OOB col carry-in = 1)
//   edge  = row & ~erode
// Wave-shfl scan (1 barrier) -> ordered point writes (row-major ==
// jnp.nonzero). ebm keeps only bits of row-major rank < KE (the reference
// only ever sees the first KE points as targets). cnt = FULL count (divisor).
// ---------------------------------------------------------------------------
__global__ void __launch_bounds__(1024) edge_fused(
        const float* __restrict__ gth, const float* __restrict__ pred,
        float2* __restrict__ gpts, float2* __restrict__ ppts,
        u64* __restrict__ ebm,
        int* __restrict__ gcnt, int* __restrict__ pcnt) {
    int b = blockIdx.x;                 // 0..31  (tensor*16 + slice)
    int tensor = b >> 4;
    int slice = b & 15;
    const float* img = (tensor ? pred : gth) + slice * HWSZ;
    float2* pts = (tensor ? ppts : gpts) + slice * KE;
    int* cnt = (tensor ? pcnt : gcnt) + slice;
    u64* eb = ebm + (size_t)b * 1024;   // 256 rows x 4 words

    int tid = threadIdx.x;
    __shared__ u64 bm_l[1024];          // [row][word4], 8 KB
    __shared__ int wsum[4];

    // ---- Phase 1: binarize + pack (4 rows / iteration, coalesced) ----
    int prow = tid >> 8;                // 0..3 (wave-uniform)
    int pcol = tid & 255;
    int wword = (tid >> 6) & 3;
    int plane = tid & 63;
#pragma unroll 8
    for (int i = 0; i < 64; ++i) {
        int r = i * 4 + prow;
        float v = img[r * WW + pcol];
        u64 bal = __ballot(v > 0.5f);
        if (plane == 0) bm_l[r * 4 + wword] = bal;
    }
    __syncthreads();

    // ---- Phase 2: edge bits + scan (thread = row, tid < 256) ----
    u64 e[4];
    int mycnt = 0, incl = 0;
    int row = tid, lane = tid & 63, wv = tid >> 6;
    if (tid < 256) {
        u64 vc[4], va[4], vb[4];
#pragma unroll
        for (int w = 0; w < 4; ++w) {
            vc[w] = bm_l[row * 4 + w];
            va[w] = (row > 0) ? bm_l[(row - 1) * 4 + w] : ~0ull;
            vb[w] = (row < HH - 1) ? bm_l[(row + 1) * 4 + w] : ~0ull;
        }
        u64 vert[4];
#pragma unroll
        for (int w = 0; w < 4; ++w) vert[w] = va[w] & vc[w] & vb[w];
#pragma unroll
        for (int w = 0; w < 4; ++w) {
            u64 left  = (vert[w] << 1) | ((w > 0) ? (vert[w - 1] >> 63) : 1ull);
            u64 right = (vert[w] >> 1) | (((w < 3) ? (vert[w + 1] & 1ull) : 1ull) << 63);
            e[w] = vc[w] & ~(vert[w] & left & right);
        }
        mycnt = __popcll(e[0]) + __popcll(e[1]) + __popcll(e[2]) + __popcll(e[3]);

        incl = mycnt;                   // wave-level inclusive scan
        for (int d = 1; d < 64; d <<= 1) {
            int n = __shfl_up(incl, d, 64);
            if (lane >= d) incl += n;
        }
        if (lane == 63) wsum[wv] = incl;
    }
    __syncthreads();
    if (tid < 256) {
        int wpre = 0;
        for (int k = 0; k < 4; ++k) wpre += (k < wv) ? wsum[k] : 0;
        int off = wpre + incl - mycnt;  // exclusive prefix (row-major rank)

        // Truncated edge bitmap: keep only bits with rank < KE.
        int rem = KE - off;
        u64 t[4];
        if (rem >= mycnt) {
#pragma unroll
            for (int w = 0; w < 4; ++w) t[w] = e[w];
        } else if (rem <= 0) {
#pragma unroll
            for (int w = 0; w < 4; ++w) t[w] = 0ull;
        } else {
            int k = rem;
#pragma unroll
            for (int w = 0; w < 4; ++w) {
                int pc = __popcll(e[w]);
                if (k >= pc) { t[w] = e[w]; k -= pc; }
                else {
                    u64 bits = e[w], keep = 0ull;
                    for (int i = 0; i < k; ++i) {
                        u64 low = bits & (~bits + 1ull);
                        keep |= low;
                        bits ^= low;
                    }
                    t[w] = keep;
                    k = 0;
                }
            }
        }
#pragma unroll
        for (int w = 0; w < 4; ++w) eb[row * 4 + w] = t[w];

        // Ordered point-list writes (queries; first KE in row-major order).
        int o = off;
#pragma unroll
        for (int w = 0; w < 4; ++w) {
            u64 bits = e[w];
            while (bits) {
                int l = __ffsll((long long)bits) - 1;
                bits &= bits - 1;
                if (o < KE) pts[o] = make_float2((float)row, (float)(w * 64 + l));
                ++o;
            }
        }
        if (row == HH - 1) *cnt = wpre + incl;
    }
}

// ---------------------------------------------------------------------------
// word_dist: distance from position p (may be <0 or >63) to the nearest set
// bit of w; GSENT if w empty. (r6-proven)
// ---------------------------------------------------------------------------
__device__ __forceinline__ int word_dist(u64 w, int p) {
    if (w == 0) return GSENT;
    int lo = __ffsll((long long)w) - 1;    // lowest set bit
    int hi = 63 - __clzll((long long)w);   // highest set bit
    if (p <= lo) return lo - p;
    if (p >= hi) return p - hi;
    u64 up = w >> p;                        // bits >= p (nonzero: hi > p)
    int du = __ffsll((long long)up) - 1;
    u64 dn = w << (63 - p);                 // bits <= p (nonzero: lo < p)
    int dd = __clzll((long long)dn);
    return min(du, dd);
}

// ---------------------------------------------------------------------------
// K2: vertical EDT, fully parallel (r6-proven, verbatim). 32 maps x 8
// row-blocks = 256 blocks x 256 threads. Stage the 8 KB edge bitmap in LDS
// (broadcast reads). Thread = column: gather the column's 256 bits into 4
// registers, then for each of the block's 32 rows compute G[r][c] = min over
// 4 words of word_dist. Coalesced u16 stores (L2-hot).
// ---------------------------------------------------------------------------
__global__ void __launch_bounds__(256) edt_vert(
        const u64* __restrict__ ebm, u16* __restrict__ G16) {
    int map = blockIdx.x >> 3;
    int rblk = blockIdx.x & 7;
    const u64* eb = ebm + (size_t)map * 1024;
    u16* G = G16 + (size_t)map * HWSZ;

    __shared__ u64 ebl[1024];
    int tid = threadIdx.x;
    for (int i = tid; i < 1024; i += 256) ebl[i] = eb[i];
    __syncthreads();

    int c = tid, cw = c >> 6, cb = c & 63;
    u64 w0 = 0, w1 = 0, w2 = 0, w3 = 0;
#pragma unroll 4
    for (int r = 0; r < 64; ++r) {
        w0 |= ((ebl[(r      ) * 4 + cw] >> cb) & 1ull) << r;
        w1 |= ((ebl[(r +  64) * 4 + cw] >> cb) & 1ull) << r;
        w2 |= ((ebl[(r + 128) * 4 + cw] >> cb) & 1ull) << r;
        w3 |= ((ebl[(r + 192) * 4 + cw] >> cb) & 1ull) << r;
    }

    int r0 = rblk * RPB;
#pragma unroll 4
    for (int i = 0; i < RPB; ++i) {
        int r = r0 + i;
        int d = word_dist(w0, r);
        d = min(d, word_dist(w1, r - 64));
        d = min(d, word_dist(w2, r - 128));
        d = min(d, word_dist(w3, r - 192));
        G[r * WW + c] = (u16)min(d, GSENT);
    }
}

// ---------------------------------------------------------------------------
// K3: per-query NN distance via column scan of the vertical EDT (r6-proven,
// verbatim). Grid = 32 (slice,dir) x 64 chunks of 64 queries = 2048 blocks
// x 64 thr. d2(q) = min_{c'} ((c-c')^2 + G[r][c']^2) -- exact integers,
// fixed 256 candidates, 32 independent int4 loads -> deep MLP, no
// divergence. Plain partial store, no atomics.
// ---------------------------------------------------------------------------
__global__ void __launch_bounds__(64) nn_gather(
        const float2* __restrict__ gpts, const float2* __restrict__ ppts,
        const int* __restrict__ gcnt, const int* __restrict__ pcnt,
        const u16* __restrict__ G16, float* __restrict__ partial) {
    int b = blockIdx.x;                 // sd*NCH + chunk
    int chunk = b & (NCH - 1);
    int sd = b >> 6;                    // slice*2 + dir
    int dir = sd & 1;
    int slice = sd >> 1;
    int tid = threadIdx.x;

    int qfull = dir ? pcnt[slice] : gcnt[slice];
    int qc = min(qfull, KE);
    int qi = chunk * 64 + tid;

    float val = 0.0f;
    if (qi < qc) {
        const float2* q = (dir ? ppts : gpts) + slice * KE;
        int tt = dir ? 0 : 1;           // target map tensor
        const u16* G = G16 + (size_t)(tt * 16 + slice) * HWSZ;
        float2 qp = q[qi];
        int r = (int)qp.x, c = (int)qp.y;
        const int4* grow = (const int4*)(G + r * WW);   // 256 u16 = 32 int4
        int m = 0x7fffffff;
#pragma unroll
        for (int j = 0; j < 32; ++j) {
            int4 v = grow[j];
            int base = j * 8;
#define STEP(word, k0)                                                      \
            {                                                               \
                int g0 = (word) & 0xffff;                                   \
                int g1 = (int)(((unsigned)(word)) >> 16);                   \
                int dc0 = c - (base + k0);                                  \
                int dc1 = c - (base + k0 + 1);                              \
                m = min(m, dc0 * dc0 + g0 * g0);                            \
                m = min(m, dc1 * dc1 + g1 * g1);                            \
            }
            STEP(v.x, 0) STEP(v.y, 2) STEP(v.z, 4) STEP(v.w, 6)
#undef STEP
        }
        val = sqrtf((float)m);
    }
    for (int s = 32; s > 0; s >>= 1) val += __shfl_xor(val, s, 64);
    if (tid == 0) partial[b] = val;
}

// ---------------------------------------------------------------------------
// K4: fold 2048 partials -> per-slice ahd -> loss -> nanmean (r6-proven,
// verbatim). 1 block x 512 threads.
// ---------------------------------------------------------------------------
__global__ void __launch_bounds__(512) finalize3(
        const int* __restrict__ gcnt, const int* __restrict__ pcnt,
        const float* __restrict__ partial, float* __restrict__ out) {
    int tid = threadIdx.x;
    float v = partial[tid * 4] + partial[tid * 4 + 1] +
              partial[tid * 4 + 2] + partial[tid * 4 + 3];
    v += __shfl_xor(v, 1, 16);
    v += __shfl_xor(v, 2, 16);
    v += __shfl_xor(v, 4, 16);
    v += __shfl_xor(v, 8, 16);
    __shared__ float sdsum[32];
    if ((tid & 15) == 0) sdsum[tid >> 4] = v;
    __syncthreads();
    if (tid == 0) {
        float sum = 0.0f;
        int nvalid = 0;
        for (int s = 0; s < NSLICE; ++s) {
            int ng = gcnt[s];
            int np_ = pcnt[s];
            if (ng > 0 && np_ > 0) {
                float ahd = 0.5f * (sdsum[s * 2 + 0] / (float)ng +
                                    sdsum[s * 2 + 1] / (float)np_);
                sum += 1.0f - 1.0f / (1.0f + ahd);
                nvalid++;
            }
        }
        out[0] = nvalid ? (sum / (float)nvalid) : NAN;
    }
}

// ---------------------------------------------------------------------------
// Workspace layout (bytes):
//   [0,       256K)    ebm    : 2 x 16 x 256 x 4 u64  (truncated edge bitmaps)
//   [262144,  768K)    gpts   : 16 x 4096 float2
//   [786432,  1.25M)   ppts   : 16 x 4096 float2
//   [1310720, 5505024) G16    : 32 maps x 256 x 256 u16 (vertical EDT)
//   [5505024, +64)     gcnt   : 16 int
//   [5505088, +64)     pcnt   : 16 int
//   [5505152, +8K)     partial: 2048 float
// ---------------------------------------------------------------------------
extern "C" void kernel_launch(void* const* d_in, const int* in_sizes, int n_in,
                              void* d_out, int out_size, void* d_ws, size_t ws_size,
                              hipStream_t stream) {
    const float* gth = (const float*)d_in[0];
    const float* pred = (const float*)d_in[1];
    float* out = (float*)d_out;
    char* ws = (char*)d_ws;

    u64* ebm = (u64*)(ws);
    float2* gpts = (float2*)(ws + 262144);
    float2* ppts = (float2*)(ws + 786432);
    u16* G16 = (u16*)(ws + 1310720);
    int* gcnt = (int*)(ws + 5505024);
    int* pcnt = (int*)(ws + 5505088);
    float* partial = (float*)(ws + 5505152);

    edge_fused<<<32, 1024, 0, stream>>>(gth, pred, gpts, ppts, ebm, gcnt, pcnt);
    edt_vert<<<256, 256, 0, stream>>>(ebm, G16);
    nn_gather<<<NSLICE * 2 * NCH, 64, 0, stream>>>(gpts, ppts, gcnt, pcnt,
                                                   G16, partial);
    finalize3<<<1, 512, 0, stream>>>(gcnt, pcnt, partial, out);
}